// Round 2
// baseline (890.920 us; speedup 1.0000x reference)
//
#include <hip/hip_runtime.h>
#include <math.h>

// Problem constants (fixed by reference): D=128, H=8, dh=16.

typedef __attribute__((ext_vector_type(8))) short short8;   // 8 x bf16
typedef __attribute__((ext_vector_type(4))) float f32x4;

__device__ __forceinline__ unsigned short f2bf(float x) {
    unsigned int u = __float_as_uint(x);
    return (unsigned short)((u + 0x7FFFu + ((u >> 16) & 1u)) >> 16);  // RNE
}

// ---------------- QKV projection: 8 rows per block, fp32 ----------------
__global__ __launch_bounds__(128) void qkv_kernel(
    const float* __restrict__ x, const float* __restrict__ WQ,
    const float* __restrict__ WK, const float* __restrict__ WV,
    float* __restrict__ Q, float* __restrict__ K, float* __restrict__ V,
    int N)
{
    const int t = threadIdx.x;
    const int r0 = blockIdx.x * 8;
    __shared__ float xs[8][128];
#pragma unroll
    for (int r = 0; r < 8; ++r)
        xs[r][t] = (r0 + r < N) ? x[(size_t)(r0 + r) * 128 + t] : 0.f;
    __syncthreads();

    float aq[8] = {0}, ak[8] = {0}, av[8] = {0};
#pragma unroll 2
    for (int k4 = 0; k4 < 32; ++k4) {
        const float* wq = WQ + (size_t)(k4 * 4) * 128 + t;
        const float* wk = WK + (size_t)(k4 * 4) * 128 + t;
        const float* wv = WV + (size_t)(k4 * 4) * 128 + t;
        float q0 = wq[0], q1 = wq[128], q2 = wq[256], q3 = wq[384];
        float k0 = wk[0], k1 = wk[128], k2 = wk[256], k3 = wk[384];
        float v0 = wv[0], v1 = wv[128], v2 = wv[256], v3 = wv[384];
#pragma unroll
        for (int r = 0; r < 8; ++r) {
            float4 xv = *(const float4*)&xs[r][k4 * 4];
            aq[r] += xv.x * q0 + xv.y * q1 + xv.z * q2 + xv.w * q3;
            ak[r] += xv.x * k0 + xv.y * k1 + xv.z * k2 + xv.w * k3;
            av[r] += xv.x * v0 + xv.y * v1 + xv.z * v2 + xv.w * v3;
        }
    }
#pragma unroll
    for (int r = 0; r < 8; ++r) {
        if (r0 + r < N) {
            const size_t o = (size_t)(r0 + r) * 128 + t;
            Q[o] = aq[r]; K[o] = ak[r]; V[o] = av[r];
        }
    }
}

// ---------------- WE -> WE^T bf16 (once per launch) ----------------
__global__ __launch_bounds__(256) void wet_kernel(
    const float* __restrict__ WE, unsigned short* __restrict__ WEt)
{
    const int i = blockIdx.x * 256 + threadIdx.x;  // i = n*128 + k
    const int n = i >> 7, k = i & 127;
    WEt[i] = f2bf(WE[k * 128 + n]);
}

// ---------------- Eh GEMM (bf16 MFMA) + fused score epilogue ----------------
// v3: 32-edge tile. LDS = union{A-bf16 8.7KB, eh-fp32 16.9KB} ~= 17.2KB ->
// 8 blocks/CU (wave cap) = ~100% occupancy; was 4 blocks (34.3KB) at 43%.
// B (WEt, 32KB, L1/L2-resident) read directly from global. Epilogue is one
// (edge,head) pair per thread, fully parallel gathers. Math is bitwise
// identical to v2 (same per-row MFMA sequence, fp32 epilogue).
#define ASTRIDE 136
#define ESTRIDE 132

__global__ __launch_bounds__(256, 8) void eh_score_kernel(
    const float* __restrict__ ea, const unsigned short* __restrict__ WEt,
    const float* __restrict__ Q, const float* __restrict__ K,
    const int* __restrict__ src, const int* __restrict__ dst,
    float* __restrict__ score, int E)
{
    union Sm {
        unsigned short A[32 * ASTRIDE];   // 8704 B (bf16 edge_attr tile)
        float eh[32 * ESTRIDE];           // 16896 B (fp32 Eh tile)
    };
    __shared__ Sm sm;
    __shared__ int ssrc[32], sdst[32];
    const int t = threadIdx.x;
    const long e0 = (long)blockIdx.x * 32;

    // Stage A tile (32 edges x 128 feats, fp32 -> bf16) into LDS.
#pragma unroll
    for (int kk = 0; kk < 4; ++kk) {
        const int f = t + kk * 256;
        const int row = f >> 5, c4 = (f & 31) * 4;
        float4 v = make_float4(0.f, 0.f, 0.f, 0.f);
        if (e0 + row < E) v = *(const float4*)&ea[(size_t)(e0 + row) * 128 + c4];
        unsigned long long pk =  (unsigned long long)f2bf(v.x)
                              | ((unsigned long long)f2bf(v.y) << 16)
                              | ((unsigned long long)f2bf(v.z) << 32)
                              | ((unsigned long long)f2bf(v.w) << 48);
        *(unsigned long long*)&sm.A[row * ASTRIDE + c4] = pk;
    }
    if (t < 32) {
        const long e = e0 + t;
        ssrc[t] = (e < E) ? src[e] : 0;
        sdst[t] = (e < E) ? dst[e] : 0;
    }
    __syncthreads();

    const int w = t >> 6, l = t & 63;
    const int rb = (w >> 1) * 16, cb = (w & 1) * 64;
    const int lr = l & 15, quad = l >> 4;

    f32x4 acc[4];
#pragma unroll
    for (int j = 0; j < 4; ++j) acc[j] = (f32x4){0.f, 0.f, 0.f, 0.f};

#pragma unroll
    for (int kb = 0; kb < 4; ++kb) {
        const int k0 = kb * 32 + quad * 8;
        short8 a0 = *(const short8*)&sm.A[(rb + lr) * ASTRIDE + k0];
        // B fragments straight from global (WEt is 32KB, L1/L2-resident).
        short8 b0 = *(const short8*)&WEt[(cb + lr) * 128 + k0];
        short8 b1 = *(const short8*)&WEt[(cb + 16 + lr) * 128 + k0];
        short8 b2 = *(const short8*)&WEt[(cb + 32 + lr) * 128 + k0];
        short8 b3 = *(const short8*)&WEt[(cb + 48 + lr) * 128 + k0];
        acc[0] = __builtin_amdgcn_mfma_f32_16x16x32_bf16(a0, b0, acc[0], 0, 0, 0);
        acc[1] = __builtin_amdgcn_mfma_f32_16x16x32_bf16(a0, b1, acc[1], 0, 0, 0);
        acc[2] = __builtin_amdgcn_mfma_f32_16x16x32_bf16(a0, b2, acc[2], 0, 0, 0);
        acc[3] = __builtin_amdgcn_mfma_f32_16x16x32_bf16(a0, b3, acc[3], 0, 0, 0);
    }
    __syncthreads();  // A dead; reuse LDS for Eh fp32

    // C/D layout (measured m89/m91): col = lane&15, row = quad*4 + reg.
#pragma unroll
    for (int ni = 0; ni < 4; ++ni)
#pragma unroll
        for (int r = 0; r < 4; ++r)
            sm.eh[(rb + quad * 4 + r) * ESTRIDE + cb + ni * 16 + lr] = acc[ni][r];
    __syncthreads();

    // Epilogue: 256 (edge,head) pairs, exactly 1 per thread, fully parallel.
    // Lane group of 8 (h=0..7) covers one edge's full 512B K/Q row coalesced;
    // score stores are fully coalesced.
    const int e = t >> 3, h = t & 7;
    const long ge = e0 + e;
    if (ge < E) {
        const float* kp = K + (size_t)ssrc[e] * 128 + h * 16;
        const float* qp = Q + (size_t)sdst[e] * 128 + h * 16;
        const float* ep = &sm.eh[e * ESTRIDE + h * 16];
        float s = 0.f;
#pragma unroll
        for (int j = 0; j < 4; ++j) {
            float4 kv = *(const float4*)&kp[j * 4];
            float4 qv = *(const float4*)&qp[j * 4];
            float4 ev = *(const float4*)&ep[j * 4];
            s += kv.x * qv.x * ev.x + kv.y * qv.y * ev.y +
                 kv.z * qv.z * ev.z + kv.w * qv.w * ev.w;
        }
        score[ge * 8 + h] = __expf(fminf(fmaxf(s * 0.25f, -5.f), 5.f));
    }
}

// ---------------- Counting sort of edges by dst ----------------
__global__ __launch_bounds__(256) void hist_kernel(
    const int* __restrict__ dst, int* __restrict__ counts, int E)
{
    const int e = blockIdx.x * 256 + threadIdx.x;
    if (e < E) atomicAdd(&counts[dst[e]], 1);
}

// 256-chunk exclusive scan (Hillis-Steele). chunksums may be null.
__global__ __launch_bounds__(256) void scan_chunk_kernel(
    const int* __restrict__ in, int* __restrict__ excl,
    int* __restrict__ chunksums, int n)
{
    __shared__ int sm[256];
    const int t = threadIdx.x;
    const int i = blockIdx.x * 256 + t;
    const int v = (i < n) ? in[i] : 0;
    sm[t] = v;
    __syncthreads();
#pragma unroll
    for (int off = 1; off < 256; off <<= 1) {
        const int a = (t >= off) ? sm[t - off] : 0;
        __syncthreads();
        sm[t] += a;
        __syncthreads();
    }
    if (i < n) excl[i] = sm[t] - v;
    if (t == 255 && chunksums) chunksums[blockIdx.x] = sm[255];
}

__global__ __launch_bounds__(256) void add_offsets_kernel(
    int* __restrict__ excl, int* __restrict__ cursor,
    const int* __restrict__ chunkoff, int n)
{
    const int i = blockIdx.x * 256 + threadIdx.x;
    if (i < n) {
        const int v = excl[i] + chunkoff[blockIdx.x];
        excl[i] = v;      // seg_start
        cursor[i] = v;    // bump cursor for fill
    }
}

__global__ __launch_bounds__(256) void fill_perm_kernel(
    const int* __restrict__ dst, int* __restrict__ cursor,
    int* __restrict__ perm, int E)
{
    const int e = blockIdx.x * 256 + threadIdx.x;
    if (e < E) {
        const int slot = atomicAdd(&cursor[dst[e]], 1);
        perm[slot] = e;
    }
}

// -------- Segmented gather: one wave per node; fused h + BN stats --------
__global__ __launch_bounds__(256) void aggregate_kernel(
    const float* __restrict__ V, const float* __restrict__ score,
    const int* __restrict__ src, const int* __restrict__ perm,
    const int* __restrict__ seg_start, const int* __restrict__ counts,
    const float* __restrict__ x, float* __restrict__ out,
    float* __restrict__ sums, int N)
{
    const int t = threadIdx.x;
    const int w = t >> 6, lane = t & 63;
    const int ha = lane >> 4, hb = 4 + (lane >> 4);
    float s1a = 0.f, s1b = 0.f, s2a = 0.f, s2b = 0.f;

    for (int node = blockIdx.x * 4 + w; node < N; node += gridDim.x * 4) {
        const int beg = seg_start[node];
        const int cnt = counts[node];
        float acc0 = 0.f, acc1 = 0.f, za = 0.f, zb = 0.f;
        for (int j = 0; j < cnt; ++j) {
            const int e = perm[beg + j];
            const int s = src[e];
            const float sa = score[(size_t)e * 8 + ha];
            const float sb = score[(size_t)e * 8 + hb];
            acc0 += sa * V[(size_t)s * 128 + lane];
            acc1 += sb * V[(size_t)s * 128 + 64 + lane];
            za += sa; zb += sb;
        }
        const size_t o = (size_t)node * 128 + lane;
        const float hv0 = x[o] + acc0 / (za + 1e-6f);
        const float hv1 = x[o + 64] + acc1 / (zb + 1e-6f);
        out[o] = hv0;
        out[o + 64] = hv1;
        s1a += hv0; s1b += hv1;
        s2a += hv0 * hv0; s2b += hv1 * hv1;
    }

    __shared__ float red[4][128];
    red[w][lane] = s1a; red[w][lane + 64] = s1b;
    __syncthreads();
    if (t < 128) atomicAdd(&sums[t], red[0][t] + red[1][t] + red[2][t] + red[3][t]);
    __syncthreads();
    red[w][lane] = s2a; red[w][lane + 64] = s2b;
    __syncthreads();
    if (t < 128) atomicAdd(&sums[128 + t], red[0][t] + red[1][t] + red[2][t] + red[3][t]);
}

__global__ void bn_scale_kernel(
    const float* __restrict__ sums,
    const float* __restrict__ gamma, const float* __restrict__ beta,
    float* __restrict__ sb, int N)
{
    const int c = threadIdx.x;  // 128 threads
    const float invN = 1.0f / (float)N;
    const float mean = sums[c] * invN;
    const float var = sums[128 + c] * invN - mean * mean;
    const float sc = gamma[c] * rsqrtf(var + 1e-5f);
    sb[c] = sc;
    sb[128 + c] = beta[c] - mean * sc;
}

__global__ __launch_bounds__(256) void bn_apply_kernel(
    float* hw, const float* __restrict__ sb, size_t total)
{
    __shared__ float ssb[256];
    ssb[threadIdx.x] = sb[threadIdx.x];
    __syncthreads();
    const size_t n4 = total / 4;
    float4* h4 = (float4*)hw;
    for (size_t i = (size_t)blockIdx.x * blockDim.x + threadIdx.x; i < n4;
         i += (size_t)gridDim.x * blockDim.x) {
        const int c4 = (int)(i & 31) * 4;
        float4 v = h4[i];
        v.x = v.x * ssb[c4 + 0] + ssb[128 + c4 + 0];
        v.y = v.y * ssb[c4 + 1] + ssb[128 + c4 + 1];
        v.z = v.z * ssb[c4 + 2] + ssb[128 + c4 + 2];
        v.w = v.w * ssb[c4 + 3] + ssb[128 + c4 + 3];
        h4[i] = v;
    }
}

extern "C" void kernel_launch(void* const* d_in, const int* in_sizes, int n_in,
                              void* d_out, int out_size, void* d_ws, size_t ws_size,
                              hipStream_t stream)
{
    const float* x         = (const float*)d_in[0];
    const float* edge_attr = (const float*)d_in[1];
    const float* WQ        = (const float*)d_in[2];
    const float* WK        = (const float*)d_in[3];
    const float* WV        = (const float*)d_in[4];
    const float* WE        = (const float*)d_in[5];
    const float* gamma     = (const float*)d_in[6];
    const float* beta      = (const float*)d_in[7];
    const int*   eidx      = (const int*)d_in[8];

    const int N = in_sizes[0] / 128;
    const int E = in_sizes[8] / 2;
    const int* src = eidx;       // edge_index[0]
    const int* dst = eidx + E;   // edge_index[1]

    float* ws = (float*)d_ws;
    const size_t NB = (size_t)N * 128;
    float* Q     = ws;
    float* K     = ws + NB;
    float* V     = ws + 2 * NB;
    float* score = ws + 3 * NB;                 // E*8 fp32
    float* sums  = score + (size_t)E * 8;       // 256
    float* sb    = sums + 256;                  // 256
    unsigned short* WEt = (unsigned short*)(sb + 256);     // 128*128 bf16
    int* counts    = (int*)(WEt + 128 * 128);   // N
    int* seg_start = counts + N;                // N
    int* cursor    = seg_start + N;             // N
    int* chunksums = cursor + N;                // 256
    int* chunkoff  = chunksums + 256;           // 256
    int* perm      = chunkoff + 256;            // E
    float* out = (float*)d_out;

    const int nch = (N + 255) / 256;  // 196 <= 256: single-block second-level scan

    hipMemsetAsync(counts, 0, (size_t)N * sizeof(int), stream);
    hipMemsetAsync(sums, 0, 256 * sizeof(float), stream);

    qkv_kernel<<<(N + 7) / 8, 128, 0, stream>>>(x, WQ, WK, WV, Q, K, V, N);
    wet_kernel<<<64, 256, 0, stream>>>(WE, WEt);
    eh_score_kernel<<<(E + 31) / 32, 256, 0, stream>>>(edge_attr, WEt, Q, K, src, dst,
                                                       score, E);
    // counting sort by dst
    hist_kernel<<<(E + 255) / 256, 256, 0, stream>>>(dst, counts, E);
    scan_chunk_kernel<<<nch, 256, 0, stream>>>(counts, seg_start, chunksums, N);
    scan_chunk_kernel<<<1, 256, 0, stream>>>(chunksums, chunkoff, nullptr, nch);
    add_offsets_kernel<<<nch, 256, 0, stream>>>(seg_start, cursor, chunkoff, N);
    fill_perm_kernel<<<(E + 255) / 256, 256, 0, stream>>>(dst, cursor, perm, E);
    // segmented gather + h + BN stats
    aggregate_kernel<<<3200, 256, 0, stream>>>(V, score, src, perm, seg_start, counts,
                                               x, out, sums, N);
    bn_scale_kernel<<<1, 128, 0, stream>>>(sums, gamma, beta, sb, N);
    bn_apply_kernel<<<2048, 256, 0, stream>>>(out, sb, NB);
}

// Round 3
// 851.084 us; speedup vs baseline: 1.0468x; 1.0468x over previous
//
#include <hip/hip_runtime.h>
#include <math.h>

// Problem constants (fixed by reference): D=128, H=8, dh=16.

typedef __attribute__((ext_vector_type(8))) short short8;   // 8 x bf16
typedef __attribute__((ext_vector_type(4))) float f32x4;

__device__ __forceinline__ unsigned short f2bf(float x) {
    unsigned int u = __float_as_uint(x);
    return (unsigned short)((u + 0x7FFFu + ((u >> 16) & 1u)) >> 16);  // RNE
}

// ---------------- QKV projection: 8 rows per block, fp32 ----------------
__global__ __launch_bounds__(128) void qkv_kernel(
    const float* __restrict__ x, const float* __restrict__ WQ,
    const float* __restrict__ WK, const float* __restrict__ WV,
    float* __restrict__ Q, float* __restrict__ K, float* __restrict__ V,
    int N)
{
    const int t = threadIdx.x;
    const int r0 = blockIdx.x * 8;
    __shared__ float xs[8][128];
#pragma unroll
    for (int r = 0; r < 8; ++r)
        xs[r][t] = (r0 + r < N) ? x[(size_t)(r0 + r) * 128 + t] : 0.f;
    __syncthreads();

    float aq[8] = {0}, ak[8] = {0}, av[8] = {0};
#pragma unroll 2
    for (int k4 = 0; k4 < 32; ++k4) {
        const float* wq = WQ + (size_t)(k4 * 4) * 128 + t;
        const float* wk = WK + (size_t)(k4 * 4) * 128 + t;
        const float* wv = WV + (size_t)(k4 * 4) * 128 + t;
        float q0 = wq[0], q1 = wq[128], q2 = wq[256], q3 = wq[384];
        float k0 = wk[0], k1 = wk[128], k2 = wk[256], k3 = wk[384];
        float v0 = wv[0], v1 = wv[128], v2 = wv[256], v3 = wv[384];
#pragma unroll
        for (int r = 0; r < 8; ++r) {
            float4 xv = *(const float4*)&xs[r][k4 * 4];
            aq[r] += xv.x * q0 + xv.y * q1 + xv.z * q2 + xv.w * q3;
            ak[r] += xv.x * k0 + xv.y * k1 + xv.z * k2 + xv.w * k3;
            av[r] += xv.x * v0 + xv.y * v1 + xv.z * v2 + xv.w * v3;
        }
    }
#pragma unroll
    for (int r = 0; r < 8; ++r) {
        if (r0 + r < N) {
            const size_t o = (size_t)(r0 + r) * 128 + t;
            Q[o] = aq[r]; K[o] = ak[r]; V[o] = av[r];
        }
    }
}

// ---------------- WE -> WE^T bf16 (once per launch) ----------------
__global__ __launch_bounds__(256) void wet_kernel(
    const float* __restrict__ WE, unsigned short* __restrict__ WEt)
{
    const int i = blockIdx.x * 256 + threadIdx.x;  // i = n*128 + k
    const int n = i >> 7, k = i & 127;
    WEt[i] = f2bf(WE[k * 128 + n]);
}

// ---------------- Eh GEMM (bf16 MFMA) + fused score epilogue ----------------
// v4 = v2 structure (64-edge tile, 4 blocks/CU; measured best at 182us) with
// one change: scores are stored to SORTED positions via eslot so that the
// aggregate kernel reads them as a coalesced stream (no gather, no perm hop).
#define ASTRIDE 136
#define ESTRIDE 132

__global__ __launch_bounds__(256, 4) void eh_score_kernel(
    const float* __restrict__ ea, const unsigned short* __restrict__ WEt,
    const float* __restrict__ Q, const float* __restrict__ K,
    const int* __restrict__ src, const int* __restrict__ dst,
    const int* __restrict__ eslot,
    float* __restrict__ score, int E)
{
    union Sm {
        unsigned short A[64 * ASTRIDE];   // 17408 B (bf16 edge_attr tile)
        float eh[64 * ESTRIDE];           // 33792 B (fp32 Eh tile)
    };
    __shared__ Sm sm;
    __shared__ int ssrc[64], sdst[64], sslot[64];
    const int t = threadIdx.x;
    const long e0 = (long)blockIdx.x * 64;

    // Stage A tile (64 edges x 128 feats, fp32 -> bf16) into LDS.
#pragma unroll
    for (int kk = 0; kk < 8; ++kk) {
        const int f = t + kk * 256;
        const int row = f >> 5, c4 = (f & 31) * 4;
        float4 v = make_float4(0.f, 0.f, 0.f, 0.f);
        if (e0 + row < E) v = *(const float4*)&ea[(size_t)(e0 + row) * 128 + c4];
        unsigned long long pk =  (unsigned long long)f2bf(v.x)
                              | ((unsigned long long)f2bf(v.y) << 16)
                              | ((unsigned long long)f2bf(v.z) << 32)
                              | ((unsigned long long)f2bf(v.w) << 48);
        *(unsigned long long*)&sm.A[row * ASTRIDE + c4] = pk;
    }
    if (t < 64) {
        const long e = e0 + t;
        ssrc[t]  = (e < E) ? src[e] : 0;
        sdst[t]  = (e < E) ? dst[e] : 0;
        sslot[t] = (e < E) ? eslot[e] : 0;
    }
    __syncthreads();

    const int w = t >> 6, l = t & 63;
    const int rb = (w >> 1) * 32, cb = (w & 1) * 64;
    const int lr = l & 15, quad = l >> 4;

    f32x4 acc[2][4];
#pragma unroll
    for (int i = 0; i < 2; ++i)
#pragma unroll
        for (int j = 0; j < 4; ++j) acc[i][j] = (f32x4){0.f, 0.f, 0.f, 0.f};

#pragma unroll
    for (int kb = 0; kb < 4; ++kb) {
        const int k0 = kb * 32 + quad * 8;
        short8 a0 = *(const short8*)&sm.A[(rb + lr) * ASTRIDE + k0];
        short8 a1 = *(const short8*)&sm.A[(rb + 16 + lr) * ASTRIDE + k0];
        // B fragments straight from global (WEt is 32KB, L1/L2-resident).
        short8 b0 = *(const short8*)&WEt[(cb + lr) * 128 + k0];
        short8 b1 = *(const short8*)&WEt[(cb + 16 + lr) * 128 + k0];
        short8 b2 = *(const short8*)&WEt[(cb + 32 + lr) * 128 + k0];
        short8 b3 = *(const short8*)&WEt[(cb + 48 + lr) * 128 + k0];
        acc[0][0] = __builtin_amdgcn_mfma_f32_16x16x32_bf16(a0, b0, acc[0][0], 0, 0, 0);
        acc[0][1] = __builtin_amdgcn_mfma_f32_16x16x32_bf16(a0, b1, acc[0][1], 0, 0, 0);
        acc[0][2] = __builtin_amdgcn_mfma_f32_16x16x32_bf16(a0, b2, acc[0][2], 0, 0, 0);
        acc[0][3] = __builtin_amdgcn_mfma_f32_16x16x32_bf16(a0, b3, acc[0][3], 0, 0, 0);
        acc[1][0] = __builtin_amdgcn_mfma_f32_16x16x32_bf16(a1, b0, acc[1][0], 0, 0, 0);
        acc[1][1] = __builtin_amdgcn_mfma_f32_16x16x32_bf16(a1, b1, acc[1][1], 0, 0, 0);
        acc[1][2] = __builtin_amdgcn_mfma_f32_16x16x32_bf16(a1, b2, acc[1][2], 0, 0, 0);
        acc[1][3] = __builtin_amdgcn_mfma_f32_16x16x32_bf16(a1, b3, acc[1][3], 0, 0, 0);
    }
    __syncthreads();  // A dead; reuse LDS for Eh fp32

    // C/D layout (measured m89/m91): col = lane&15, row = quad*4 + reg.
#pragma unroll
    for (int mi = 0; mi < 2; ++mi)
#pragma unroll
        for (int ni = 0; ni < 4; ++ni)
#pragma unroll
            for (int r = 0; r < 4; ++r)
                sm.eh[(rb + mi * 16 + quad * 4 + r) * ESTRIDE + cb + ni * 16 + lr] =
                    acc[mi][ni][r];
    __syncthreads();

    // Epilogue: 512 (edge,head) pairs, 2 per thread, fully parallel gathers.
    // Store goes to the sorted slot so aggregate reads scores as a stream.
#pragma unroll
    for (int pp = 0; pp < 2; ++pp) {
        const int p = t + pp * 256;
        const int e = p >> 3, h = p & 7;
        const long ge = e0 + e;
        if (ge < E) {
            const float* kp = K + (size_t)ssrc[e] * 128 + h * 16;
            const float* qp = Q + (size_t)sdst[e] * 128 + h * 16;
            const float* ep = &sm.eh[e * ESTRIDE + h * 16];
            float s = 0.f;
#pragma unroll
            for (int j = 0; j < 4; ++j) {
                float4 kv = *(const float4*)&kp[j * 4];
                float4 qv = *(const float4*)&qp[j * 4];
                float4 ev = *(const float4*)&ep[j * 4];
                s += kv.x * qv.x * ev.x + kv.y * qv.y * ev.y +
                     kv.z * qv.z * ev.z + kv.w * qv.w * ev.w;
            }
            score[(size_t)sslot[e] * 8 + h] = __expf(fminf(fmaxf(s * 0.25f, -5.f), 5.f));
        }
    }
}

// ---------------- Counting sort of edges by dst ----------------
__global__ __launch_bounds__(256) void hist_kernel(
    const int* __restrict__ dst, int* __restrict__ counts, int E)
{
    const int e = blockIdx.x * 256 + threadIdx.x;
    if (e < E) atomicAdd(&counts[dst[e]], 1);
}

// 256-chunk exclusive scan (Hillis-Steele). chunksums may be null.
__global__ __launch_bounds__(256) void scan_chunk_kernel(
    const int* __restrict__ in, int* __restrict__ excl,
    int* __restrict__ chunksums, int n)
{
    __shared__ int sm[256];
    const int t = threadIdx.x;
    const int i = blockIdx.x * 256 + t;
    const int v = (i < n) ? in[i] : 0;
    sm[t] = v;
    __syncthreads();
#pragma unroll
    for (int off = 1; off < 256; off <<= 1) {
        const int a = (t >= off) ? sm[t - off] : 0;
        __syncthreads();
        sm[t] += a;
        __syncthreads();
    }
    if (i < n) excl[i] = sm[t] - v;
    if (t == 255 && chunksums) chunksums[blockIdx.x] = sm[255];
}

__global__ __launch_bounds__(256) void add_offsets_kernel(
    int* __restrict__ excl, int* __restrict__ cursor,
    const int* __restrict__ chunkoff, int n)
{
    const int i = blockIdx.x * 256 + threadIdx.x;
    if (i < n) {
        const int v = excl[i] + chunkoff[blockIdx.x];
        excl[i] = v;      // seg_start
        cursor[i] = v;    // bump cursor for fill
    }
}

// Writes the inverse permutation (eslot) and the sorted src array so that
// downstream passes stream instead of chasing perm->src/score pointers.
__global__ __launch_bounds__(256) void fill_sort_kernel(
    const int* __restrict__ src, const int* __restrict__ dst,
    int* __restrict__ cursor, int* __restrict__ eslot,
    int* __restrict__ srcs, int E)
{
    const int e = blockIdx.x * 256 + threadIdx.x;
    if (e < E) {
        const int slot = atomicAdd(&cursor[dst[e]], 1);
        eslot[e] = slot;       // coalesced write
        srcs[slot] = src[e];   // 4B scatter
    }
}

// -------- Segmented gather: one wave per node; fused h + BN stats --------
// v2: srcs and score are pre-sorted by dst -> both are coalesced streams;
// only V[s] remains a gather (chain depth 1). 1-ahead software pipeline
// keeps the next V-row in flight while accumulating the current one.
__global__ __launch_bounds__(256) void aggregate_kernel(
    const float* __restrict__ V, const float* __restrict__ score,
    const int* __restrict__ srcs,
    const int* __restrict__ seg_start, const int* __restrict__ counts,
    const float* __restrict__ x, float* __restrict__ out,
    float* __restrict__ sums, int N)
{
    const int t = threadIdx.x;
    const int w = t >> 6, lane = t & 63;
    const int ha = lane >> 4, hb = 4 + (lane >> 4);
    float s1a = 0.f, s1b = 0.f, s2a = 0.f, s2b = 0.f;

    for (int node = blockIdx.x * 4 + w; node < N; node += gridDim.x * 4) {
        const int beg = seg_start[node];
        const int cnt = counts[node];
        float acc0 = 0.f, acc1 = 0.f, za = 0.f, zb = 0.f;
        if (cnt > 0) {
            int sA = srcs[beg];
            float saA = score[(size_t)beg * 8 + ha];
            float sbA = score[(size_t)beg * 8 + hb];
            const float* vA = V + (size_t)sA * 128;
            float vA0 = vA[lane], vA1 = vA[lane + 64];
            for (int j = 1; j < cnt; ++j) {
                const int sB = srcs[beg + j];
                const float saB = score[(size_t)(beg + j) * 8 + ha];
                const float sbB = score[(size_t)(beg + j) * 8 + hb];
                const float* vB = V + (size_t)sB * 128;
                const float vB0 = vB[lane], vB1 = vB[lane + 64];
                acc0 += saA * vA0; za += saA;
                acc1 += sbA * vA1; zb += sbA;
                saA = saB; sbA = sbB; vA0 = vB0; vA1 = vB1;
            }
            acc0 += saA * vA0; za += saA;
            acc1 += sbA * vA1; zb += sbA;
        }
        const size_t o = (size_t)node * 128 + lane;
        const float hv0 = x[o] + acc0 / (za + 1e-6f);
        const float hv1 = x[o + 64] + acc1 / (zb + 1e-6f);
        out[o] = hv0;
        out[o + 64] = hv1;
        s1a += hv0; s1b += hv1;
        s2a += hv0 * hv0; s2b += hv1 * hv1;
    }

    __shared__ float red[4][128];
    red[w][lane] = s1a; red[w][lane + 64] = s1b;
    __syncthreads();
    if (t < 128) atomicAdd(&sums[t], red[0][t] + red[1][t] + red[2][t] + red[3][t]);
    __syncthreads();
    red[w][lane] = s2a; red[w][lane + 64] = s2b;
    __syncthreads();
    if (t < 128) atomicAdd(&sums[128 + t], red[0][t] + red[1][t] + red[2][t] + red[3][t]);
}

__global__ void bn_scale_kernel(
    const float* __restrict__ sums,
    const float* __restrict__ gamma, const float* __restrict__ beta,
    float* __restrict__ sb, int N)
{
    const int c = threadIdx.x;  // 128 threads
    const float invN = 1.0f / (float)N;
    const float mean = sums[c] * invN;
    const float var = sums[128 + c] * invN - mean * mean;
    const float sc = gamma[c] * rsqrtf(var + 1e-5f);
    sb[c] = sc;
    sb[128 + c] = beta[c] - mean * sc;
}

__global__ __launch_bounds__(256) void bn_apply_kernel(
    float* hw, const float* __restrict__ sb, size_t total)
{
    __shared__ float ssb[256];
    ssb[threadIdx.x] = sb[threadIdx.x];
    __syncthreads();
    const size_t n4 = total / 4;
    float4* h4 = (float4*)hw;
    for (size_t i = (size_t)blockIdx.x * blockDim.x + threadIdx.x; i < n4;
         i += (size_t)gridDim.x * blockDim.x) {
        const int c4 = (int)(i & 31) * 4;
        float4 v = h4[i];
        v.x = v.x * ssb[c4 + 0] + ssb[128 + c4 + 0];
        v.y = v.y * ssb[c4 + 1] + ssb[128 + c4 + 1];
        v.z = v.z * ssb[c4 + 2] + ssb[128 + c4 + 2];
        v.w = v.w * ssb[c4 + 3] + ssb[128 + c4 + 3];
        h4[i] = v;
    }
}

extern "C" void kernel_launch(void* const* d_in, const int* in_sizes, int n_in,
                              void* d_out, int out_size, void* d_ws, size_t ws_size,
                              hipStream_t stream)
{
    const float* x         = (const float*)d_in[0];
    const float* edge_attr = (const float*)d_in[1];
    const float* WQ        = (const float*)d_in[2];
    const float* WK        = (const float*)d_in[3];
    const float* WV        = (const float*)d_in[4];
    const float* WE        = (const float*)d_in[5];
    const float* gamma     = (const float*)d_in[6];
    const float* beta      = (const float*)d_in[7];
    const int*   eidx      = (const int*)d_in[8];

    const int N = in_sizes[0] / 128;
    const int E = in_sizes[8] / 2;
    const int* src = eidx;       // edge_index[0]
    const int* dst = eidx + E;   // edge_index[1]

    float* ws = (float*)d_ws;
    const size_t NB = (size_t)N * 128;
    float* Q     = ws;
    float* K     = ws + NB;
    float* V     = ws + 2 * NB;
    float* score = ws + 3 * NB;                 // E*8 fp32 (sorted order)
    float* sums  = score + (size_t)E * 8;       // 256
    float* sb    = sums + 256;                  // 256
    unsigned short* WEt = (unsigned short*)(sb + 256);     // 128*128 bf16
    int* counts    = (int*)(WEt + 128 * 128);   // N
    int* seg_start = counts + N;                // N
    int* cursor    = seg_start + N;             // N
    int* chunksums = cursor + N;                // 256
    int* chunkoff  = chunksums + 256;           // 256
    int* eslot     = chunkoff + 256;            // E (inverse perm)
    int* srcs      = eslot + E;                 // E (src sorted by dst)
    float* out = (float*)d_out;

    const int nch = (N + 255) / 256;  // 196 <= 256: single-block second-level scan

    hipMemsetAsync(counts, 0, (size_t)N * sizeof(int), stream);
    hipMemsetAsync(sums, 0, 256 * sizeof(float), stream);

    qkv_kernel<<<(N + 7) / 8, 128, 0, stream>>>(x, WQ, WK, WV, Q, K, V, N);
    wet_kernel<<<64, 256, 0, stream>>>(WE, WEt);
    // counting sort by dst (only needs edge_index; runs before eh_score so
    // eh_score can store scores directly in sorted order)
    hist_kernel<<<(E + 255) / 256, 256, 0, stream>>>(dst, counts, E);
    scan_chunk_kernel<<<nch, 256, 0, stream>>>(counts, seg_start, chunksums, N);
    scan_chunk_kernel<<<1, 256, 0, stream>>>(chunksums, chunkoff, nullptr, nch);
    add_offsets_kernel<<<nch, 256, 0, stream>>>(seg_start, cursor, chunkoff, N);
    fill_sort_kernel<<<(E + 255) / 256, 256, 0, stream>>>(src, dst, cursor, eslot,
                                                          srcs, E);
    eh_score_kernel<<<(E + 63) / 64, 256, 0, stream>>>(edge_attr, WEt, Q, K, src, dst,
                                                       eslot, score, E);
    // segmented gather + h + BN stats
    aggregate_kernel<<<3200, 256, 0, stream>>>(V, score, srcs, seg_start, counts,
                                               x, out, sums, N);
    bn_scale_kernel<<<1, 128, 0, stream>>>(sums, gamma, beta, sb, N);
    bn_apply_kernel<<<2048, 256, 0, stream>>>(out, sb, NB);
}